// Round 26
// baseline (569.178 us; speedup 1.0000x reference)
//
#include <hip/hip_runtime.h>
#include <hip/hip_bf16.h>
#include <math.h>

typedef __bf16 bf16;
typedef __attribute__((ext_vector_type(8))) __bf16 bf16x8;
typedef __attribute__((ext_vector_type(4))) float f32x4;
typedef __attribute__((ext_vector_type(8))) float f32x8;

// ---- static problem config ----
#define NTOK   36864      // 8*48*96
#define CDIM   512
#define NHEAD  16
#define HD     32
#define NWIN   32         // windows per lon-group (nPl*nLat = 4*8)
#define NLON   8          // lon groups
#define WTOK   144        // tokens per window (2*6*12)
#define TBL    3312       // bias table rows (4*36*23)

// async global->LDS, 16B per lane, LDS dest = wave-uniform base + lane*16
#define GLOAD_LDS16(g, l) __builtin_amdgcn_global_load_lds( \
    (const __attribute__((address_space(1))) void*)(const void*)(g), \
    (__attribute__((address_space(3))) void*)(l), 16, 0, 0)

// permuted row r -> source token index (fuses roll(-1,-3,-6) + window partition)
__device__ __forceinline__ int src_token(int r) {
    int ww_ = r % 12; int q = r / 12;
    int wl_ = q % 6;  q /= 6;
    int wp_ = q & 1;  q >>= 1;
    int lat_g = q & 7; q >>= 3;
    int pl_g = q & 3;  q >>= 2;
    int lon_g = q;                       // 0..7
    int pl  = pl_g * 2 + wp_ + 1;  if (pl  >= 8)  pl  -= 8;
    int lat = lat_g * 6 + wl_ + 3; if (lat >= 48) lat -= 48;
    int lon = lon_g * 12 + ww_ + 6; if (lon >= 96) lon -= 96;
    return (pl * 48 + lat) * 96 + lon;
}

__device__ __forceinline__ float gelu_exact(float x) {
    return 0.5f * x * (1.0f + erff(x * 0.70710678118654752f));
}

// ---- ALL transposes in ONE launch: 4 weights (fp32 RxCc -> bf16 CcxR) + bias
// table (fp32 [3312][512] -> fp32 [512][3312]). fp32 LDS tile serves both paths. ----
__global__ __launch_bounds__(256) void transpose_all(const float* __restrict__ qkv_w,
                                                     const float* __restrict__ proj_w,
                                                     const float* __restrict__ w1,
                                                     const float* __restrict__ w2,
                                                     const float* __restrict__ btab,
                                                     bf16* __restrict__ wtq,
                                                     bf16* __restrict__ wtp,
                                                     bf16* __restrict__ wt1,
                                                     bf16* __restrict__ wt2,
                                                     float* __restrict__ tableT) {
    __shared__ float tile[32][33];
    int bid = blockIdx.x;
    int tx = threadIdx.x & 31, ty = threadIdx.x >> 5;   // ty 0..7

    if (bid >= 3072) {   // bias table: [TBL][512] -> [512][TBL], tiles 104 x 16
        int ti = bid - 3072;
        int i0 = (ti % 104) * 32, w0 = (ti / 104) * 32;
#pragma unroll
        for (int r = 0; r < 32; r += 8)
            if (i0 + ty + r < TBL) tile[ty + r][tx] = btab[(size_t)(i0 + ty + r) * 512 + w0 + tx];
        __syncthreads();
#pragma unroll
        for (int r = 0; r < 32; r += 8)
            if (i0 + tx < TBL) tableT[(size_t)(w0 + ty + r) * TBL + i0 + tx] = tile[tx][ty + r];
        return;
    }

    const float* in; bf16* outp; int R, Cc, ti;
    if (bid < 768)       { in = qkv_w;  outp = wtq; R = 512;  Cc = 1536; ti = bid; }
    else if (bid < 1024) { in = proj_w; outp = wtp; R = 512;  Cc = 512;  ti = bid - 768; }
    else if (bid < 2048) { in = w1;     outp = wt1; R = 512;  Cc = 2048; ti = bid - 1024; }
    else                 { in = w2;     outp = wt2; R = 2048; Cc = 512;  ti = bid - 2048; }
    int gx = Cc >> 5;
    int c0 = (ti % gx) * 32, r0 = (ti / gx) * 32;
#pragma unroll
    for (int i = 0; i < 32; i += 8)
        tile[ty + i][tx] = in[(size_t)(r0 + ty + i) * Cc + c0 + tx];
    __syncthreads();
#pragma unroll
    for (int i = 0; i < 32; i += 8)
        outp[(size_t)(c0 + ty + i) * R + r0 + tx] = (bf16)tile[tx][ty + i];
}

// ---- LayerNorm over C=512 (fp32 in, bf16 out), one wave per row;
//      PERM=true fuses roll+partition gather ----
template<bool PERM>
__global__ __launch_bounds__(256) void ln_kernel(const float* __restrict__ in,
                                                 const float* __restrict__ w,
                                                 const float* __restrict__ b,
                                                 bf16* __restrict__ out) {
    int r = blockIdx.x * 4 + (threadIdx.x >> 6);
    int lane = threadIdx.x & 63;
    int s = PERM ? src_token(r) : r;
    f32x8 v8 = *(const f32x8*)(in + (size_t)s * CDIM + lane * 8);
    float sum = 0.f, sq = 0.f;
#pragma unroll
    for (int i = 0; i < 8; ++i) { sum += v8[i]; sq += v8[i] * v8[i]; }
#pragma unroll
    for (int m = 1; m < 64; m <<= 1) { sum += __shfl_xor(sum, m); sq += __shfl_xor(sq, m); }
    float mean = sum * (1.f / 512.f);
    float var  = sq  * (1.f / 512.f) - mean * mean;
    float rstd = rsqrtf(var + 1e-5f);
    f32x8 w8 = *(const f32x8*)(w + lane * 8);
    f32x8 b8 = *(const f32x8*)(b + lane * 8);
    bf16x8 o8;
#pragma unroll
    for (int i = 0; i < 8; ++i)
        o8[i] = (bf16)((v8[i] - mean) * rstd * w8[i] + b8[i]);
    *(bf16x8*)(out + (size_t)r * CDIM + lane * 8) = o8;
}

// ---- GEMM (measured best config): D = A @ Bt^T + bias ----
// 2-phase double-buffered global_load_lds staging + bijective XCD swizzle.
// 1-D grid: nwg = (N/128)*(M/128), gx = N/128.
// EPI 0: Cout(bf16) = D
// EPI 1: Cout(bf16) = gelu(D)
// EPI 2: Cout(f32)[src(row)] = X[src(row)] + D   (proj scatter-residual; N=512)
// EPI 3: Cout(f32)[row] += D                      (mlp2 in-place residual; N=512)
template<int EPI>
__global__ __launch_bounds__(256) void gemm_bt(const bf16* __restrict__ A,
                                               const bf16* __restrict__ Bt,
                                               const float* __restrict__ bias,
                                               void* __restrict__ Cout_,
                                               const float* __restrict__ X,
                                               int K, int N, int gx) {
    __shared__ bf16 As[2 * 128 * 32];
    __shared__ bf16 Bs[2 * 128 * 32];
    int t = threadIdx.x;
    int wid = t >> 6, lane = t & 63;
    int wr = wid >> 1, wc = wid & 1;
    int g = lane >> 4, cl = lane & 15;

    // bijective XCD swizzle: XCD k (= orig%8) processes contiguous chunk
    int nwg = gridDim.x, orig = blockIdx.x;
    int wg = orig;
    if ((nwg & 7) == 0) {
        int cpx = nwg >> 3;
        wg = (orig & 7) * cpx + (orig >> 3);
    }
    int m0 = (wg / gx) * 128, n0 = (wg % gx) * 128;
    f32x4 acc[4][4] = {};

    // staging geometry: wave wid covers rows [wid*16, wid*16+16) and +64
    int srow = wid * 16 + (lane >> 2);
    int scol = (lane & 3) * 8;
    const bf16* Ag0 = A  + (size_t)(m0 + srow) * K + scol;
    const bf16* Ag1 = Ag0 + (size_t)64 * K;
    const bf16* Bg0 = Bt + (size_t)(n0 + srow) * K + scol;
    const bf16* Bg1 = Bg0 + (size_t)64 * K;
    int ldsoff = wid * 16 * 32;   // elements

    // prologue: stage K-tile 0 into buffer 0
    GLOAD_LDS16(Ag0, As + ldsoff);
    GLOAD_LDS16(Ag1, As + 64 * 32 + ldsoff);
    GLOAD_LDS16(Bg0, Bs + ldsoff);
    GLOAD_LDS16(Bg1, Bs + 64 * 32 + ldsoff);
    __syncthreads();   // drains vmcnt + barrier

    int nt = K >> 5, cur = 0;
    for (int kt = 0; kt < nt; ++kt) {
        if (kt + 1 < nt) {                       // prefetch next K-tile into other buffer
            int k1 = (kt + 1) << 5;
            bf16* Ad = As + (cur ^ 1) * 4096;
            bf16* Bd = Bs + (cur ^ 1) * 4096;
            GLOAD_LDS16(Ag0 + k1, Ad + ldsoff);
            GLOAD_LDS16(Ag1 + k1, Ad + 64 * 32 + ldsoff);
            GLOAD_LDS16(Bg0 + k1, Bd + ldsoff);
            GLOAD_LDS16(Bg1 + k1, Bd + 64 * 32 + ldsoff);
        }
        const bf16* Ar = As + cur * 4096;
        const bf16* Br = Bs + cur * 4096;
        bf16x8 af[4], bfv[4];
#pragma unroll
        for (int i = 0; i < 4; ++i)
            af[i]  = *(const bf16x8*)(Ar + (wr * 64 + i * 16 + cl) * 32 + g * 8);
#pragma unroll
        for (int i = 0; i < 4; ++i)
            bfv[i] = *(const bf16x8*)(Br + (wc * 64 + i * 16 + cl) * 32 + g * 8);
#pragma unroll
        for (int mi = 0; mi < 4; ++mi)
#pragma unroll
            for (int ni = 0; ni < 4; ++ni)
                acc[mi][ni] = __builtin_amdgcn_mfma_f32_16x16x32_bf16(af[mi], bfv[ni], acc[mi][ni], 0, 0, 0);
        __syncthreads();   // ds_reads done (lgkmcnt) + prefetch landed (vmcnt) + barrier
        cur ^= 1;
    }

#pragma unroll
    for (int mi = 0; mi < 4; ++mi) {
#pragma unroll
        for (int j = 0; j < 4; ++j) {
            int row = m0 + wr * 64 + mi * 16 + g * 4 + j;
            int srw = 0;
            if (EPI == 2) srw = src_token(row);
#pragma unroll
            for (int ni = 0; ni < 4; ++ni) {
                int col = n0 + wc * 64 + ni * 16 + cl;
                float v = acc[mi][ni][j] + bias[col];
                if (EPI == 1) v = gelu_exact(v);
                if (EPI == 0 || EPI == 1) {
                    ((bf16*)Cout_)[(size_t)row * N + col] = (bf16)v;
                } else if (EPI == 2) {
                    size_t o = (size_t)srw * CDIM + col;
                    ((float*)Cout_)[o] = X[o] + v;
                } else { // EPI == 3
                    size_t o = (size_t)row * N + col;
                    ((float*)Cout_)[o] += v;
                }
            }
        }
    }
}

// ---- MFMA windowed attention; 1-D grid 4096 with bijective XCD swizzle so all
// 16 head-blocks of a window (sharing its 442KB qkv slice) land on one XCD ----
__global__ __launch_bounds__(256) void attn_mfma(const bf16* __restrict__ qkv,
                                                 const float* __restrict__ tableT,
                                                 bf16* __restrict__ obuf) {
    int wgs = (blockIdx.x & 7) * 512 + (blockIdx.x >> 3);   // 4096 % 8 == 0, bijective
    int h  = wgs & 15;
    int w  = (wgs >> 4) & 31;
    int b_ = wgs >> 9;
    int t = threadIdx.x, wid = t >> 6, lane = t & 63;
    int g = lane >> 4, cl = lane & 15;
    size_t base = ((size_t)b_ * NWIN + w) * WTOK;

    __shared__ bf16 P[WTOK * 168];    // 48384 B; first 23040 B reused for qs,ks
    __shared__ bf16 vT[32 * 168];     // v transposed [d][tok], cols 144..167 zeroed
    __shared__ float bias_s[TBL];     // per-(w,h) bias slice
    bf16* qs = P;                     // [144][40]
    bf16* ks = P + WTOK * 40;         // [144][40]

    const bf16* qg = qkv + base * 1536 + h * 32;
    for (int tok = t >> 2; tok < WTOK; tok += 64) {
        int c8 = (t & 3) * 8;
        *(bf16x8*)(qs + tok * 40 + c8) = *(const bf16x8*)(qg + (size_t)tok * 1536 + c8);
        *(bf16x8*)(ks + tok * 40 + c8) = *(const bf16x8*)(qg + 512 + (size_t)tok * 1536 + c8);
        bf16x8 v8 = *(const bf16x8*)(qg + 1024 + (size_t)tok * 1536 + c8);
#pragma unroll
        for (int i = 0; i < 8; ++i) vT[(c8 + i) * 168 + tok] = v8[i];
    }
    for (int z = t; z < 32 * 24; z += 256) vT[(z / 24) * 168 + 144 + (z % 24)] = (bf16)0.f;
    const float* tb = tableT + (size_t)(w * 16 + h) * TBL;
    for (int i = t; i < TBL; i += 256) bias_s[i] = tb[i];
    __syncthreads();

    f32x4 sacc[3][9] = {};
    bf16x8 kf[9];
#pragma unroll
    for (int ct = 0; ct < 9; ++ct)
        kf[ct] = *(const bf16x8*)(ks + (ct * 16 + cl) * 40 + g * 8);
#pragma unroll
    for (int rti = 0; rti < 3; ++rti) {
        int rt = wid + rti * 4;
        if (rt < 9) {
            bf16x8 qf = *(const bf16x8*)(qs + (rt * 16 + cl) * 40 + g * 8);
#pragma unroll
            for (int ct = 0; ct < 9; ++ct)
                sacc[rti][ct] = __builtin_amdgcn_mfma_f32_16x16x32_bf16(qf, kf[ct], sacc[rti][ct], 0, 0, 0);
        }
    }
    __syncthreads();   // q,k dead; P region reusable

    for (int z = t; z < WTOK * 24; z += 256) P[(z / 24) * 168 + 144 + (z % 24)] = (bf16)0.f;

    int bm[9];
#pragma unroll
    for (int ct = 0; ct < 9; ++ct) {
        int m = ct * 16 + cl;
        int wm = m % 12, tm = m / 12, hm = tm % 6, zm = tm / 6;
        bm[ct] = zm * 1656 + hm * 138 + 11 - wm;
    }

    const float scale = 0.17677669529663689f;   // 32^-0.5
    float rinv[3][4];
#pragma unroll
    for (int rti = 0; rti < 3; ++rti) {
        int rt = wid + rti * 4;
        if (rt < 9) {
#pragma unroll
            for (int j = 0; j < 4; ++j) {
                int row = rt * 16 + g * 4 + j;
                int wn = row % 12, tn = row / 12, hn = tn % 6, zn = tn / 6;
                int an = zn * 828 + hn * 23 + wn;
                float mx = -1e30f;
#pragma unroll
                for (int ct = 0; ct < 9; ++ct) {
                    float v = sacc[rti][ct][j] * scale + bias_s[an + bm[ct]];
                    sacc[rti][ct][j] = v;
                    mx = fmaxf(mx, v);
                }
                for (int msk = 1; msk < 16; msk <<= 1) mx = fmaxf(mx, __shfl_xor(mx, msk));
                float sm = 0.f;
#pragma unroll
                for (int ct = 0; ct < 9; ++ct) {
                    float p = __expf(sacc[rti][ct][j] - mx);
                    sm += p;
                    P[row * 168 + ct * 16 + cl] = (bf16)p;
                }
                for (int msk = 1; msk < 16; msk <<= 1) sm += __shfl_xor(sm, msk);
                rinv[rti][j] = 1.f / sm;
            }
        }
    }
    __syncthreads();   // P fully written

#pragma unroll
    for (int rti = 0; rti < 3; ++rti) {
        int rt = wid + rti * 4;
        if (rt < 9) {
            f32x4 oacc[2] = {};
#pragma unroll
            for (int ks_ = 0; ks_ < 5; ++ks_) {
                bf16x8 pf = *(const bf16x8*)(P + (rt * 16 + cl) * 168 + ks_ * 32 + g * 8);
#pragma unroll
                for (int c2 = 0; c2 < 2; ++c2) {
                    bf16x8 vf = *(const bf16x8*)(vT + (c2 * 16 + cl) * 168 + ks_ * 32 + g * 8);
                    oacc[c2] = __builtin_amdgcn_mfma_f32_16x16x32_bf16(pf, vf, oacc[c2], 0, 0, 0);
                }
            }
#pragma unroll
            for (int c2 = 0; c2 < 2; ++c2)
#pragma unroll
                for (int j = 0; j < 4; ++j) {
                    int row = rt * 16 + g * 4 + j;
                    obuf[(base + row) * CDIM + h * 32 + c2 * 16 + cl] =
                        (bf16)(oacc[c2][j] * rinv[rti][j]);
                }
        }
    }
}

extern "C" void kernel_launch(void* const* d_in, const int* in_sizes, int n_in,
                              void* d_out, int out_size, void* d_ws, size_t ws_size,
                              hipStream_t stream) {
    const float* x       = (const float*)d_in[0];
    const float* n1w     = (const float*)d_in[1];
    const float* n1b     = (const float*)d_in[2];
    const float* qkv_w   = (const float*)d_in[3];
    const float* qkv_b   = (const float*)d_in[4];
    const float* proj_w  = (const float*)d_in[5];
    const float* proj_b  = (const float*)d_in[6];
    const float* btab    = (const float*)d_in[7];
    const float* n2w     = (const float*)d_in[8];
    const float* n2b     = (const float*)d_in[9];
    const float* mlp_w1  = (const float*)d_in[10];
    const float* mlp_b1  = (const float*)d_in[11];
    const float* mlp_w2  = (const float*)d_in[12];
    const float* mlp_b2  = (const float*)d_in[13];
    float* out = (float*)d_out;

    // workspace layout (bytes) — all intermediates bf16 unless noted
    const size_t OFF_HBUF = 0;                  //  37,748,736  LN1(perm) / LN2 out
    const size_t OFF_QKV  = 37748736;           // 113,246,208  qkv; later mlp-hidden
    const size_t OFF_TT   = 150994944;          //   6,782,976  tableT fp32 (dead after attn)
    const size_t OFF_OBUF = 188743680;          //  37,748,736  attn out
    const size_t OFF_WTQ  = 226492416;          //   1,572,864  qkv_w^T  (1536x512)
    const size_t OFF_WTP  = 228065280;          //     524,288  proj_w^T (512x512)
    const size_t OFF_WT1  = 228589568;          //   2,097,152  mlp_w1^T (2048x512)
    const size_t OFF_WT2  = 230686720;          //   2,097,152  mlp_w2^T (512x2048)
    const size_t NEED     = 232783872;

    if (ws_size < NEED) return;   // leaves d_out zeroed -> absmax 5.65625 signals ws too small

    char* ws = (char*)d_ws;
    bf16*  hbuf   = (bf16*)(ws + OFF_HBUF);
    bf16*  qkvbuf = (bf16*)(ws + OFF_QKV);
    bf16*  midbuf = qkvbuf;
    float* tableT = (float*)(ws + OFF_TT);
    bf16*  obuf   = (bf16*)(ws + OFF_OBUF);
    bf16*  wtq    = (bf16*)(ws + OFF_WTQ);
    bf16*  wtp    = (bf16*)(ws + OFF_WTP);
    bf16*  wt1    = (bf16*)(ws + OFF_WT1);
    bf16*  wt2    = (bf16*)(ws + OFF_WT2);

    // 1. ALL transposes (4 weights + bias table) in one launch
    transpose_all<<<3072 + 1664, 256, 0, stream>>>(qkv_w, proj_w, mlp_w1, mlp_w2, btab,
                                                   wtq, wtp, wt1, wt2, tableT);

    // 2. LN1 + roll + window partition (fp32 -> bf16)
    ln_kernel<true><<<NTOK / 4, 256, 0, stream>>>(x, n1w, n1b, hbuf);

    // 3. QKV GEMM: (36864x512)@(512x1536) -> bf16   [grid 12*288, 1-D + swizzle]
    gemm_bt<0><<<12 * 288, 256, 0, stream>>>(hbuf, wtq, qkv_b, qkvbuf, nullptr, 512, 1536, 12);

    // 4. attention (MFMA, 1-D grid + XCD swizzle)
    attn_mfma<<<4096, 256, 0, stream>>>(qkvbuf, tableT, obuf);

    // 5. proj GEMM + reverse-partition scatter + residual -> d_out (fp32) holds x1
    gemm_bt<2><<<4 * 288, 256, 0, stream>>>(obuf, wtp, proj_b, out, x, 512, 512, 4);

    // 6. LN2 (fp32 -> bf16)
    ln_kernel<false><<<NTOK / 4, 256, 0, stream>>>(out, n2w, n2b, hbuf);

    // 7. MLP1 + exact GELU -> bf16
    gemm_bt<1><<<16 * 288, 256, 0, stream>>>(hbuf, wt1, mlp_b1, midbuf, nullptr, 512, 2048, 16);

    // 8. MLP2 + residual into d_out (fp32)
    gemm_bt<3><<<4 * 288, 256, 0, stream>>>(midbuf, wt2, mlp_b2, out, nullptr, 2048, 512, 4);
}

// Round 27
// 559.388 us; speedup vs baseline: 1.0175x; 1.0175x over previous
//
#include <hip/hip_runtime.h>
#include <hip/hip_bf16.h>
#include <math.h>

typedef __bf16 bf16;
typedef __attribute__((ext_vector_type(8))) __bf16 bf16x8;
typedef __attribute__((ext_vector_type(4))) float f32x4;
typedef __attribute__((ext_vector_type(8))) float f32x8;

// ---- static problem config ----
#define NTOK   36864      // 8*48*96
#define CDIM   512
#define NHEAD  16
#define HD     32
#define NWIN   32         // windows per lon-group (nPl*nLat = 4*8)
#define NLON   8          // lon groups
#define WTOK   144        // tokens per window (2*6*12)
#define TBL    3312       // bias table rows (4*36*23)

// async global->LDS, 16B per lane, LDS dest = wave-uniform base + lane*16
#define GLOAD_LDS16(g, l) __builtin_amdgcn_global_load_lds( \
    (const __attribute__((address_space(1))) void*)(const void*)(g), \
    (__attribute__((address_space(3))) void*)(l), 16, 0, 0)

// permuted row r -> source token index (fuses roll(-1,-3,-6) + window partition)
__device__ __forceinline__ int src_token(int r) {
    int ww_ = r % 12; int q = r / 12;
    int wl_ = q % 6;  q /= 6;
    int wp_ = q & 1;  q >>= 1;
    int lat_g = q & 7; q >>= 3;
    int pl_g = q & 3;  q >>= 2;
    int lon_g = q;                       // 0..7
    int pl  = pl_g * 2 + wp_ + 1;  if (pl  >= 8)  pl  -= 8;
    int lat = lat_g * 6 + wl_ + 3; if (lat >= 48) lat -= 48;
    int lon = lon_g * 12 + ww_ + 6; if (lon >= 96) lon -= 96;
    return (pl * 48 + lat) * 96 + lon;
}

__device__ __forceinline__ float gelu_exact(float x) {
    return 0.5f * x * (1.0f + erff(x * 0.70710678118654752f));
}

// ---- ALL transposes in ONE launch: 4 weights (fp32 RxCc -> bf16 CcxR) + bias
// table (fp32 [3312][512] -> fp32 [512][3312]). fp32 LDS tile serves both paths. ----
__global__ __launch_bounds__(256) void transpose_all(const float* __restrict__ qkv_w,
                                                     const float* __restrict__ proj_w,
                                                     const float* __restrict__ w1,
                                                     const float* __restrict__ w2,
                                                     const float* __restrict__ btab,
                                                     bf16* __restrict__ wtq,
                                                     bf16* __restrict__ wtp,
                                                     bf16* __restrict__ wt1,
                                                     bf16* __restrict__ wt2,
                                                     float* __restrict__ tableT) {
    __shared__ float tile[32][33];
    int bid = blockIdx.x;
    int tx = threadIdx.x & 31, ty = threadIdx.x >> 5;   // ty 0..7

    if (bid >= 3072) {   // bias table: [TBL][512] -> [512][TBL], tiles 104 x 16
        int ti = bid - 3072;
        int i0 = (ti % 104) * 32, w0 = (ti / 104) * 32;
#pragma unroll
        for (int r = 0; r < 32; r += 8)
            if (i0 + ty + r < TBL) tile[ty + r][tx] = btab[(size_t)(i0 + ty + r) * 512 + w0 + tx];
        __syncthreads();
#pragma unroll
        for (int r = 0; r < 32; r += 8)
            if (i0 + tx < TBL) tableT[(size_t)(w0 + ty + r) * TBL + i0 + tx] = tile[tx][ty + r];
        return;
    }

    const float* in; bf16* outp; int R, Cc, ti;
    if (bid < 768)       { in = qkv_w;  outp = wtq; R = 512;  Cc = 1536; ti = bid; }
    else if (bid < 1024) { in = proj_w; outp = wtp; R = 512;  Cc = 512;  ti = bid - 768; }
    else if (bid < 2048) { in = w1;     outp = wt1; R = 512;  Cc = 2048; ti = bid - 1024; }
    else                 { in = w2;     outp = wt2; R = 2048; Cc = 512;  ti = bid - 2048; }
    int gx = Cc >> 5;
    int c0 = (ti % gx) * 32, r0 = (ti / gx) * 32;
#pragma unroll
    for (int i = 0; i < 32; i += 8)
        tile[ty + i][tx] = in[(size_t)(r0 + ty + i) * Cc + c0 + tx];
    __syncthreads();
#pragma unroll
    for (int i = 0; i < 32; i += 8)
        outp[(size_t)(c0 + ty + i) * R + r0 + tx] = (bf16)tile[tx][ty + i];
}

// ---- LayerNorm over C=512 (fp32 in, bf16 out), one wave per row;
//      PERM=true fuses roll+partition gather ----
template<bool PERM>
__global__ __launch_bounds__(256) void ln_kernel(const float* __restrict__ in,
                                                 const float* __restrict__ w,
                                                 const float* __restrict__ b,
                                                 bf16* __restrict__ out) {
    int r = blockIdx.x * 4 + (threadIdx.x >> 6);
    int lane = threadIdx.x & 63;
    int s = PERM ? src_token(r) : r;
    f32x8 v8 = *(const f32x8*)(in + (size_t)s * CDIM + lane * 8);
    float sum = 0.f, sq = 0.f;
#pragma unroll
    for (int i = 0; i < 8; ++i) { sum += v8[i]; sq += v8[i] * v8[i]; }
#pragma unroll
    for (int m = 1; m < 64; m <<= 1) { sum += __shfl_xor(sum, m); sq += __shfl_xor(sq, m); }
    float mean = sum * (1.f / 512.f);
    float var  = sq  * (1.f / 512.f) - mean * mean;
    float rstd = rsqrtf(var + 1e-5f);
    f32x8 w8 = *(const f32x8*)(w + lane * 8);
    f32x8 b8 = *(const f32x8*)(b + lane * 8);
    bf16x8 o8;
#pragma unroll
    for (int i = 0; i < 8; ++i)
        o8[i] = (bf16)((v8[i] - mean) * rstd * w8[i] + b8[i]);
    *(bf16x8*)(out + (size_t)r * CDIM + lane * 8) = o8;
}

// ---- GEMM (measured best config): D = A @ Bt^T + bias ----
// 2-phase double-buffered global_load_lds staging + bijective XCD swizzle.
// 1-D grid: nwg = (N/128)*(M/128), gx = N/128.
// EPI 0: Cout(bf16) = D
// EPI 1: Cout(bf16) = gelu(D)
// EPI 2: Cout(f32)[src(row)] = X[src(row)] + D   (proj scatter-residual; N=512)
// EPI 3: Cout(f32)[row] += D                      (mlp2 in-place residual; N=512)
template<int EPI>
__global__ __launch_bounds__(256) void gemm_bt(const bf16* __restrict__ A,
                                               const bf16* __restrict__ Bt,
                                               const float* __restrict__ bias,
                                               void* __restrict__ Cout_,
                                               const float* __restrict__ X,
                                               int K, int N, int gx) {
    __shared__ bf16 As[2 * 128 * 32];
    __shared__ bf16 Bs[2 * 128 * 32];
    int t = threadIdx.x;
    int wid = t >> 6, lane = t & 63;
    int wr = wid >> 1, wc = wid & 1;
    int g = lane >> 4, cl = lane & 15;

    // bijective XCD swizzle: XCD k (= orig%8) processes contiguous chunk
    int nwg = gridDim.x, orig = blockIdx.x;
    int wg = orig;
    if ((nwg & 7) == 0) {
        int cpx = nwg >> 3;
        wg = (orig & 7) * cpx + (orig >> 3);
    }
    int m0 = (wg / gx) * 128, n0 = (wg % gx) * 128;
    f32x4 acc[4][4] = {};

    // staging geometry: wave wid covers rows [wid*16, wid*16+16) and +64
    int srow = wid * 16 + (lane >> 2);
    int scol = (lane & 3) * 8;
    const bf16* Ag0 = A  + (size_t)(m0 + srow) * K + scol;
    const bf16* Ag1 = Ag0 + (size_t)64 * K;
    const bf16* Bg0 = Bt + (size_t)(n0 + srow) * K + scol;
    const bf16* Bg1 = Bg0 + (size_t)64 * K;
    int ldsoff = wid * 16 * 32;   // elements

    // prologue: stage K-tile 0 into buffer 0
    GLOAD_LDS16(Ag0, As + ldsoff);
    GLOAD_LDS16(Ag1, As + 64 * 32 + ldsoff);
    GLOAD_LDS16(Bg0, Bs + ldsoff);
    GLOAD_LDS16(Bg1, Bs + 64 * 32 + ldsoff);
    __syncthreads();   // drains vmcnt + barrier

    int nt = K >> 5, cur = 0;
    for (int kt = 0; kt < nt; ++kt) {
        if (kt + 1 < nt) {                       // prefetch next K-tile into other buffer
            int k1 = (kt + 1) << 5;
            bf16* Ad = As + (cur ^ 1) * 4096;
            bf16* Bd = Bs + (cur ^ 1) * 4096;
            GLOAD_LDS16(Ag0 + k1, Ad + ldsoff);
            GLOAD_LDS16(Ag1 + k1, Ad + 64 * 32 + ldsoff);
            GLOAD_LDS16(Bg0 + k1, Bd + ldsoff);
            GLOAD_LDS16(Bg1 + k1, Bd + 64 * 32 + ldsoff);
        }
        const bf16* Ar = As + cur * 4096;
        const bf16* Br = Bs + cur * 4096;
        bf16x8 af[4], bfv[4];
#pragma unroll
        for (int i = 0; i < 4; ++i)
            af[i]  = *(const bf16x8*)(Ar + (wr * 64 + i * 16 + cl) * 32 + g * 8);
#pragma unroll
        for (int i = 0; i < 4; ++i)
            bfv[i] = *(const bf16x8*)(Br + (wc * 64 + i * 16 + cl) * 32 + g * 8);
#pragma unroll
        for (int mi = 0; mi < 4; ++mi)
#pragma unroll
            for (int ni = 0; ni < 4; ++ni)
                acc[mi][ni] = __builtin_amdgcn_mfma_f32_16x16x32_bf16(af[mi], bfv[ni], acc[mi][ni], 0, 0, 0);
        __syncthreads();   // ds_reads done (lgkmcnt) + prefetch landed (vmcnt) + barrier
        cur ^= 1;
    }

#pragma unroll
    for (int mi = 0; mi < 4; ++mi) {
#pragma unroll
        for (int j = 0; j < 4; ++j) {
            int row = m0 + wr * 64 + mi * 16 + g * 4 + j;
            int srw = 0;
            if (EPI == 2) srw = src_token(row);
#pragma unroll
            for (int ni = 0; ni < 4; ++ni) {
                int col = n0 + wc * 64 + ni * 16 + cl;
                float v = acc[mi][ni][j] + bias[col];
                if (EPI == 1) v = gelu_exact(v);
                if (EPI == 0 || EPI == 1) {
                    ((bf16*)Cout_)[(size_t)row * N + col] = (bf16)v;
                } else if (EPI == 2) {
                    size_t o = (size_t)srw * CDIM + col;
                    ((float*)Cout_)[o] = X[o] + v;
                } else { // EPI == 3
                    size_t o = (size_t)row * N + col;
                    ((float*)Cout_)[o] += v;
                }
            }
        }
    }
}

// ---- MFMA windowed attention; 1-D grid 4096 with bijective XCD swizzle so all
// 16 head-blocks of a window (sharing its 442KB qkv slice) land on one XCD ----
__global__ __launch_bounds__(256) void attn_mfma(const bf16* __restrict__ qkv,
                                                 const float* __restrict__ tableT,
                                                 bf16* __restrict__ obuf) {
    int wgs = (blockIdx.x & 7) * 512 + (blockIdx.x >> 3);   // 4096 % 8 == 0, bijective
    int h  = wgs & 15;
    int w  = (wgs >> 4) & 31;
    int b_ = wgs >> 9;
    int t = threadIdx.x, wid = t >> 6, lane = t & 63;
    int g = lane >> 4, cl = lane & 15;
    size_t base = ((size_t)b_ * NWIN + w) * WTOK;

    __shared__ bf16 P[WTOK * 168];    // 48384 B; first 23040 B reused for qs,ks
    __shared__ bf16 vT[32 * 168];     // v transposed [d][tok], cols 144..167 zeroed
    __shared__ float bias_s[TBL];     // per-(w,h) bias slice
    bf16* qs = P;                     // [144][40]
    bf16* ks = P + WTOK * 40;         // [144][40]

    const bf16* qg = qkv + base * 1536 + h * 32;
    for (int tok = t >> 2; tok < WTOK; tok += 64) {
        int c8 = (t & 3) * 8;
        *(bf16x8*)(qs + tok * 40 + c8) = *(const bf16x8*)(qg + (size_t)tok * 1536 + c8);
        *(bf16x8*)(ks + tok * 40 + c8) = *(const bf16x8*)(qg + 512 + (size_t)tok * 1536 + c8);
        bf16x8 v8 = *(const bf16x8*)(qg + 1024 + (size_t)tok * 1536 + c8);
#pragma unroll
        for (int i = 0; i < 8; ++i) vT[(c8 + i) * 168 + tok] = v8[i];
    }
    for (int z = t; z < 32 * 24; z += 256) vT[(z / 24) * 168 + 144 + (z % 24)] = (bf16)0.f;
    const float* tb = tableT + (size_t)(w * 16 + h) * TBL;
    for (int i = t; i < TBL; i += 256) bias_s[i] = tb[i];
    __syncthreads();

    f32x4 sacc[3][9] = {};
    bf16x8 kf[9];
#pragma unroll
    for (int ct = 0; ct < 9; ++ct)
        kf[ct] = *(const bf16x8*)(ks + (ct * 16 + cl) * 40 + g * 8);
#pragma unroll
    for (int rti = 0; rti < 3; ++rti) {
        int rt = wid + rti * 4;
        if (rt < 9) {
            bf16x8 qf = *(const bf16x8*)(qs + (rt * 16 + cl) * 40 + g * 8);
#pragma unroll
            for (int ct = 0; ct < 9; ++ct)
                sacc[rti][ct] = __builtin_amdgcn_mfma_f32_16x16x32_bf16(qf, kf[ct], sacc[rti][ct], 0, 0, 0);
        }
    }
    __syncthreads();   // q,k dead; P region reusable

    for (int z = t; z < WTOK * 24; z += 256) P[(z / 24) * 168 + 144 + (z % 24)] = (bf16)0.f;

    int bm[9];
#pragma unroll
    for (int ct = 0; ct < 9; ++ct) {
        int m = ct * 16 + cl;
        int wm = m % 12, tm = m / 12, hm = tm % 6, zm = tm / 6;
        bm[ct] = zm * 1656 + hm * 138 + 11 - wm;
    }

    const float scale = 0.17677669529663689f;   // 32^-0.5
    float rinv[3][4];
#pragma unroll
    for (int rti = 0; rti < 3; ++rti) {
        int rt = wid + rti * 4;
        if (rt < 9) {
#pragma unroll
            for (int j = 0; j < 4; ++j) {
                int row = rt * 16 + g * 4 + j;
                int wn = row % 12, tn = row / 12, hn = tn % 6, zn = tn / 6;
                int an = zn * 828 + hn * 23 + wn;
                float mx = -1e30f;
#pragma unroll
                for (int ct = 0; ct < 9; ++ct) {
                    float v = sacc[rti][ct][j] * scale + bias_s[an + bm[ct]];
                    sacc[rti][ct][j] = v;
                    mx = fmaxf(mx, v);
                }
                for (int msk = 1; msk < 16; msk <<= 1) mx = fmaxf(mx, __shfl_xor(mx, msk));
                float sm = 0.f;
#pragma unroll
                for (int ct = 0; ct < 9; ++ct) {
                    float p = __expf(sacc[rti][ct][j] - mx);
                    sm += p;
                    P[row * 168 + ct * 16 + cl] = (bf16)p;
                }
                for (int msk = 1; msk < 16; msk <<= 1) sm += __shfl_xor(sm, msk);
                rinv[rti][j] = 1.f / sm;
            }
        }
    }
    __syncthreads();   // P fully written

#pragma unroll
    for (int rti = 0; rti < 3; ++rti) {
        int rt = wid + rti * 4;
        if (rt < 9) {
            f32x4 oacc[2] = {};
#pragma unroll
            for (int ks_ = 0; ks_ < 5; ++ks_) {
                bf16x8 pf = *(const bf16x8*)(P + (rt * 16 + cl) * 168 + ks_ * 32 + g * 8);
#pragma unroll
                for (int c2 = 0; c2 < 2; ++c2) {
                    bf16x8 vf = *(const bf16x8*)(vT + (c2 * 16 + cl) * 168 + ks_ * 32 + g * 8);
                    oacc[c2] = __builtin_amdgcn_mfma_f32_16x16x32_bf16(pf, vf, oacc[c2], 0, 0, 0);
                }
            }
#pragma unroll
            for (int c2 = 0; c2 < 2; ++c2)
#pragma unroll
                for (int j = 0; j < 4; ++j) {
                    int row = rt * 16 + g * 4 + j;
                    obuf[(base + row) * CDIM + h * 32 + c2 * 16 + cl] =
                        (bf16)(oacc[c2][j] * rinv[rti][j]);
                }
        }
    }
}

extern "C" void kernel_launch(void* const* d_in, const int* in_sizes, int n_in,
                              void* d_out, int out_size, void* d_ws, size_t ws_size,
                              hipStream_t stream) {
    const float* x       = (const float*)d_in[0];
    const float* n1w     = (const float*)d_in[1];
    const float* n1b     = (const float*)d_in[2];
    const float* qkv_w   = (const float*)d_in[3];
    const float* qkv_b   = (const float*)d_in[4];
    const float* proj_w  = (const float*)d_in[5];
    const float* proj_b  = (const float*)d_in[6];
    const float* btab    = (const float*)d_in[7];
    const float* n2w     = (const float*)d_in[8];
    const float* n2b     = (const float*)d_in[9];
    const float* mlp_w1  = (const float*)d_in[10];
    const float* mlp_b1  = (const float*)d_in[11];
    const float* mlp_w2  = (const float*)d_in[12];
    const float* mlp_b2  = (const float*)d_in[13];
    float* out = (float*)d_out;

    // workspace layout (bytes) — all intermediates bf16 unless noted
    const size_t OFF_HBUF = 0;                  //  37,748,736  LN1(perm) / LN2 out
    const size_t OFF_QKV  = 37748736;           // 113,246,208  qkv; later mlp-hidden
    const size_t OFF_TT   = 150994944;          //   6,782,976  tableT fp32 (dead after attn)
    const size_t OFF_OBUF = 188743680;          //  37,748,736  attn out
    const size_t OFF_WTQ  = 226492416;          //   1,572,864  qkv_w^T  (1536x512)
    const size_t OFF_WTP  = 228065280;          //     524,288  proj_w^T (512x512)
    const size_t OFF_WT1  = 228589568;          //   2,097,152  mlp_w1^T (2048x512)
    const size_t OFF_WT2  = 230686720;          //   2,097,152  mlp_w2^T (512x2048)
    const size_t NEED     = 232783872;

    if (ws_size < NEED) return;   // leaves d_out zeroed -> absmax 5.65625 signals ws too small

    char* ws = (char*)d_ws;
    bf16*  hbuf   = (bf16*)(ws + OFF_HBUF);
    bf16*  qkvbuf = (bf16*)(ws + OFF_QKV);
    bf16*  midbuf = qkvbuf;
    float* tableT = (float*)(ws + OFF_TT);
    bf16*  obuf   = (bf16*)(ws + OFF_OBUF);
    bf16*  wtq    = (bf16*)(ws + OFF_WTQ);
    bf16*  wtp    = (bf16*)(ws + OFF_WTP);
    bf16*  wt1    = (bf16*)(ws + OFF_WT1);
    bf16*  wt2    = (bf16*)(ws + OFF_WT2);

    // 1. ALL transposes (4 weights + bias table) in one launch
    transpose_all<<<3072 + 1664, 256, 0, stream>>>(qkv_w, proj_w, mlp_w1, mlp_w2, btab,
                                                   wtq, wtp, wt1, wt2, tableT);

    // 2. LN1 + roll + window partition (fp32 -> bf16)
    ln_kernel<true><<<NTOK / 4, 256, 0, stream>>>(x, n1w, n1b, hbuf);

    // 3. QKV GEMM: (36864x512)@(512x1536) -> bf16   [grid 12*288, 1-D + swizzle]
    gemm_bt<0><<<12 * 288, 256, 0, stream>>>(hbuf, wtq, qkv_b, qkvbuf, nullptr, 512, 1536, 12);

    // 4. attention (MFMA, 1-D grid + XCD swizzle)
    attn_mfma<<<4096, 256, 0, stream>>>(qkvbuf, tableT, obuf);

    // 5. proj GEMM + reverse-partition scatter + residual -> d_out (fp32) holds x1
    gemm_bt<2><<<4 * 288, 256, 0, stream>>>(obuf, wtp, proj_b, out, x, 512, 512, 4);

    // 6. LN2 (fp32 -> bf16)
    ln_kernel<false><<<NTOK / 4, 256, 0, stream>>>(out, n2w, n2b, hbuf);

    // 7. MLP1 + exact GELU -> bf16
    gemm_bt<1><<<16 * 288, 256, 0, stream>>>(hbuf, wt1, mlp_b1, midbuf, nullptr, 512, 2048, 16);

    // 8. MLP2 + residual into d_out (fp32)
    gemm_bt<3><<<4 * 288, 256, 0, stream>>>(midbuf, wt2, mlp_b2, out, nullptr, 2048, 512, 4);
}